// Round 1
// baseline (362.245 us; speedup 1.0000x reference)
//
#include <hip/hip_runtime.h>

typedef _Float16 f16;
typedef __attribute__((ext_vector_type(8))) _Float16 f16x8;
typedef __attribute__((ext_vector_type(4))) _Float16 f16x4;
typedef __attribute__((ext_vector_type(4))) float f32x4;

#define BATCH 16
#define NSEQ  2048
#define DDIM  300
#define DPK   328   // padded row length (f16 elems) for row-major Xf/Yf (zeros in [300,328))
#define DPV   304   // padded d-rows for transposed XT/YT (zeros in [300,304))
#define NTP   2056  // padded q-cols for transposed copies (zeros in [2048,2056))
#define XF_ELEMS (BATCH*NSEQ*DPK)
#define XT_ELEMS (BATCH*DPV*NTP)

__device__ __forceinline__ void gl_lds16(const void* g, void* l) {
  __builtin_amdgcn_global_load_lds((const __attribute__((address_space(1))) unsigned int*)g,
                                   (__attribute__((address_space(3))) unsigned int*)l, 16, 0, 0);
}

// ---------------------------------------------------------------------------
// Preprocess: X,Y f32 -> f16 row-major (padded) + f16 transposed (padded)
// One read of the f32 inputs; LDS 32x32 tile transpose for coalescing.
// ---------------------------------------------------------------------------
__global__ __launch_bounds__(256) void prep_kernel(const float* __restrict__ X,
                                                   const float* __restrict__ Y,
                                                   f16* __restrict__ Xf, f16* __restrict__ Yf,
                                                   f16* __restrict__ XT, f16* __restrict__ YT) {
  __shared__ float tile[32][33];
  int bz   = blockIdx.z;            // 0..31 = tensor*16 + b
  int tsel = bz >> 4, b = bz & 15;
  const float* src = tsel ? Y : X;
  f16* dF = tsel ? Yf : Xf;
  f16* dT = tsel ? YT : XT;
  int d0 = blockIdx.y * 32;         // 0..320
  int q0 = blockIdx.x * 32;         // 0..2048
  int tid = threadIdx.x;
  int c = tid & 31, rr = tid >> 5;  // 8 rows per pass

  #pragma unroll
  for (int i = 0; i < 4; ++i) {
    int qr = rr + i * 8;
    int q = q0 + qr, d = d0 + c;
    float v = 0.f;
    if (q < NSEQ && d < DDIM) v = src[(size_t)b * NSEQ * DDIM + (size_t)q * DDIM + d];
    tile[c][qr] = v;
    if (q < NSEQ && d < DPK) dF[(size_t)b * NSEQ * DPK + (size_t)q * DPK + d] = (f16)v;
  }
  __syncthreads();
  #pragma unroll
  for (int i = 0; i < 4; ++i) {
    int dr = rr + i * 8;
    int d = d0 + dr, q = q0 + c;
    if (d < DPV && q < NTP) dT[(size_t)b * DPV * NTP + (size_t)d * NTP + q] = (f16)tile[dr][c];
  }
}

// ---------------------------------------------------------------------------
// Flash attention, swapped-operand QK^T (S^T[kv][q]), fp16 MFMA 16x16x32.
// Block = 4 waves x 16 q-rows (QBLK=64); KV tile = 32 rows, single-buffered.
// Grid = 2 dirs * 16 batches * 32 qtiles = 1024, XCD-chunk swizzled.
// ---------------------------------------------------------------------------
__global__ __launch_bounds__(256) void attn_kernel(const f16* __restrict__ Xf,
                                                   const f16* __restrict__ Yf,
                                                   const f16* __restrict__ XT,
                                                   const f16* __restrict__ YT,
                                                   float* __restrict__ out) {
  __shared__ __align__(16) f16 Ksh[32][DPK];    // 20992 B; row stride 656B -> 2-way max on b128
  __shared__ __align__(16) f16 VTsh[DPV][40];   // 24320 B; row stride 80B  -> 2-way max on b128
  __shared__ __align__(16) f16 Pl[4][16][40];   // 5120 B; per-wave P buffer

  int idx = blockIdx.x;
  int swz = (idx & 7) * 128 + (idx >> 3);       // 1024 % 8 == 0: bijective XCD chunking
  int qt  = swz & 31;
  int b   = (swz >> 5) & 15;
  int dir = swz >> 9;

  const f16* Qsrc = dir ? Yf : Xf;
  const f16* Ksrc = dir ? Xf : Yf;
  const f16* Vts  = dir ? XT : YT;   // V^T source [DPV][NTP]
  const f16* Mts  = dir ? YT : XT;   // epilogue multiplier (Q^T)

  const size_t bq = (size_t)b * NSEQ * DPK;
  const size_t bt = (size_t)b * DPV * NTP;

  int tid = threadIdx.x;
  int lane = tid & 63, wid = tid >> 6;
  int l15 = lane & 15, g = lane >> 4;
  int qw = qt * 64 + wid * 16;        // this wave's q base

  // Q fragments in registers: B-operand layout, lane holds Q[q=l15][ks*32 + g*8 + j]
  f16x8 qf[10];
  {
    const f16* qrow = Qsrc + bq + (size_t)(qw + l15) * DPK + g * 8;
    #pragma unroll
    for (int ks = 0; ks < 10; ++ks) qf[ks] = *(const f16x8*)(qrow + ks * 32);
  }

  f32x4 O[19];
  #pragma unroll
  for (int i = 0; i < 19; ++i) O[i] = (f32x4){0.f, 0.f, 0.f, 0.f};
  float m = -3.0e38f, lsum = 0.f;

  const char* gK0 = (const char*)(Ksrc + bq);
  const char* gV0 = (const char*)(Vts + bt);

  #pragma unroll 1
  for (int t = 0; t < 64; ++t) {
    int kv0 = t * 32;
    // ---- stage K tile: contiguous 32x656B = 1312 chunks of 16B
    {
      const char* gK = gK0 + (size_t)kv0 * (DPK * 2);
      #pragma unroll
      for (int i = 0; i < 6; ++i) {
        int c = i * 256 + tid;
        if (c < 1312) gl_lds16(gK + c * 16, (char*)&Ksh[0][0] + c * 16);
      }
      // ---- stage V^T tile: 304 rows x 80B (64B data + 16B benign overread) = 1520 chunks
      #pragma unroll
      for (int i = 0; i < 6; ++i) {
        int c = i * 256 + tid;
        if (c < 1520) {
          int row = c / 5, slot = c - row * 5;
          const char* ga = gV0 + (size_t)row * (NTP * 2) + kv0 * 2 + slot * 16;
          gl_lds16(ga, (char*)&VTsh[0][0] + c * 16);
        }
      }
    }
    asm volatile("s_waitcnt vmcnt(0)" ::: "memory");
    __syncthreads();

    // ---- QK^T (swapped): S^T[kv][q] = K . Q^T
    f32x4 S[2];
    S[0] = (f32x4){0.f, 0.f, 0.f, 0.f};
    S[1] = (f32x4){0.f, 0.f, 0.f, 0.f};
    #pragma unroll
    for (int ks = 0; ks < 10; ++ks) {
      #pragma unroll
      for (int kvt = 0; kvt < 2; ++kvt) {
        f16x8 af = *(const f16x8*)&Ksh[kvt * 16 + l15][ks * 32 + g * 8];
        S[kvt] = __builtin_amdgcn_mfma_f32_16x16x32_f16(af, qf[ks], S[kvt], 0, 0, 0);
      }
    }

    // ---- online softmax over kv, per q-column (= l15); lane's rows kv = kvt*16 + 4g + r
    float t0 = fmaxf(fmaxf(S[0][0], S[0][1]), fmaxf(S[0][2], S[0][3]));
    float t1 = fmaxf(fmaxf(S[1][0], S[1][1]), fmaxf(S[1][2], S[1][3]));
    float tmax = fmaxf(t0, t1);
    tmax = fmaxf(tmax, __shfl_xor(tmax, 16, 64));
    tmax = fmaxf(tmax, __shfl_xor(tmax, 32, 64));
    if (__any(tmax > m + 8.0f)) {            // defer-max: rescale only on real growth
      float mnew = fmaxf(m, tmax);
      float al = __expf(m - mnew);
      lsum *= al;
      #pragma unroll
      for (int i = 0; i < 19; ++i) {
        O[i][0] *= al; O[i][1] *= al; O[i][2] *= al; O[i][3] *= al;
      }
      m = mnew;
    }
    float p[8];
    float ts = 0.f;
    #pragma unroll
    for (int kvt = 0; kvt < 2; ++kvt) {
      #pragma unroll
      for (int r = 0; r < 4; ++r) {
        float e = __expf(S[kvt][r] - m);     // bounded by e^8
        p[kvt * 4 + r] = e;
        ts += e;
      }
    }
    ts += __shfl_xor(ts, 16, 64);
    ts += __shfl_xor(ts, 32, 64);
    lsum += ts;

    // ---- P -> fp16 -> per-wave LDS [q][kv] (4 consecutive kv pack to one b64)
    #pragma unroll
    for (int kvt = 0; kvt < 2; ++kvt) {
      f16x4 ph;
      ph[0] = (f16)p[kvt * 4 + 0]; ph[1] = (f16)p[kvt * 4 + 1];
      ph[2] = (f16)p[kvt * 4 + 2]; ph[3] = (f16)p[kvt * 4 + 3];
      *(f16x4*)&Pl[wid][l15][kvt * 16 + g * 4] = ph;
    }
    asm volatile("s_waitcnt lgkmcnt(0)" ::: "memory");

    // ---- PV (swapped): O^T[d][q] += V^T . P^T
    f16x8 pb = *(const f16x8*)&Pl[wid][l15][g * 8];
    #pragma unroll
    for (int dt = 0; dt < 19; ++dt) {
      f16x8 af = *(const f16x8*)&VTsh[dt * 16 + l15][g * 8];
      O[dt] = __builtin_amdgcn_mfma_f32_16x16x32_f16(af, pb, O[dt], 0, 0, 0);
    }
    __syncthreads();
  }

  // ---- epilogue: O /= l, multiply by Q (via f16 transposed copy), store f32
  float rinv = 1.0f / lsum;
  size_t orow = (size_t)b * (4096 * 300) + (size_t)(dir * 2048 + qw + l15) * 300;
  #pragma unroll
  for (int dt = 0; dt < 19; ++dt) {
    #pragma unroll
    for (int r = 0; r < 4; ++r) {
      int d = dt * 16 + g * 4 + r;
      if (d < 300) {
        float mul = (float)Mts[bt + (size_t)d * NTP + (qw + l15)];
        out[orow + d] = O[dt][r] * rinv * mul;
      }
    }
  }
}

extern "C" void kernel_launch(void* const* d_in, const int* in_sizes, int n_in,
                              void* d_out, int out_size, void* d_ws, size_t ws_size,
                              hipStream_t stream) {
  const float* X = (const float*)d_in[0];
  const float* Y = (const float*)d_in[1];
  float* out = (float*)d_out;

  size_t need = (size_t)(2 * XF_ELEMS + 2 * XT_ELEMS) * sizeof(f16);  // ~83 MB
  if (ws_size < need) return;  // fail loudly (output stays zero) rather than corrupt

  f16* Xf = (f16*)d_ws;
  f16* Yf = Xf + XF_ELEMS;
  f16* XT = Yf + XF_ELEMS;
  f16* YT = XT + XT_ELEMS;

  prep_kernel<<<dim3(65, 11, 32), 256, 0, stream>>>(X, Y, Xf, Yf, XT, YT);
  attn_kernel<<<dim3(1024), 256, 0, stream>>>(Xf, Yf, XT, YT, out);
}